// Round 6
// baseline (168.956 us; speedup 1.0000x reference)
//
#include <hip/hip_runtime.h>
#include <math.h>

typedef __attribute__((ext_vector_type(8))) _Float16 f16x8;
typedef __attribute__((ext_vector_type(4))) float f32x4;

#define NPIX 4096
#define C_DIM 128
#define SCALE 0.08838834764831845f   // 1/sqrt(128), folded into X hi/lo split
#define ROWB 272                     // LDS bytes per key row: 256 data + 16 pad (16B-aligned, bank-shift 4)
#define TILEB (64 * ROWB)            // 17 KB per buffer

static __device__ __forceinline__ unsigned int pk2(float a, float b) {
    union { _Float16 h[2]; unsigned int u; } cv;
    cv.h[0] = (_Float16)a;
    cv.h[1] = (_Float16)b;
    return cv.u;
}

// Single fused kernel: per 64-key tile, convert native-fp32 Y -> fp16 [k][c] LDS tile
// in-block (no pre-kernel, no workspace), MFMA S^T (A=Y from LDS, B=X fp16 hi/lo in regs),
// exp-accumulate grid expectation. 256 blocks = 1 block/CU; double-buffered LDS, 1 barrier/tile.
__global__ __launch_bounds__(256, 1) void uv_fused(
    const float* __restrict__ x, const float* __restrict__ y, float* __restrict__ out)
{
    __shared__ __align__(16) char Ys[2][TILEB];

    const int t = threadIdx.x, w = t >> 6, l = t & 63;
    const int n16 = l & 15, quad = l >> 4;
    const int wg  = blockIdx.x;
    const int xcd = wg & 7;
    const int b   = xcd >> 1;                       // 2 XCDs per batch -> y panel L2-resident
    const int qt  = ((xcd & 1) << 5) | (wg >> 3);   // 0..63
    const int q0  = qt * 64;

    // ---- one-time: X B-fragments, fp16 hi/lo exact split, scale folded ----
    // B[k=quad*8+j][n=n16]: channel = cc*32+quad*8+j, query = q0+qg*16+n16
    f16x8 bh[4][4], bl[4][4];
    {
        const float* xb = x + (size_t)b * C_DIM * NPIX + q0 + n16;
        #pragma unroll
        for (int cc = 0; cc < 4; ++cc)
            #pragma unroll
            for (int qg = 0; qg < 4; ++qg) {
                f16x8 hh, ll;
                #pragma unroll
                for (int j = 0; j < 8; ++j) {
                    const float f = xb[(size_t)(cc * 32 + quad * 8 + j) * NPIX + qg * 16] * SCALE;
                    const _Float16 fh = (_Float16)f;
                    hh[j] = fh;
                    ll[j] = (_Float16)(f - (float)fh);
                }
                bh[cc][qg] = hh;
                bl[cc][qg] = ll;
            }
    }

    // this lane's channel pair (2l, 2l+1); wave w stages keys [w*16, w*16+16) of each tile
    const float* yb = y + ((size_t)b * C_DIM + 2 * l) * NPIX + w * 16;

    // ---- preamble: stage tile 0 into buf 0 ----
    #pragma unroll
    for (int u = 0; u < 4; ++u) {
        const float4 a0 = *(const float4*)(yb + u * 4);
        const float4 a1 = *(const float4*)(yb + NPIX + u * 4);
        const float* f0 = (const float*)&a0;
        const float* f1 = (const float*)&a1;
        #pragma unroll
        for (int j = 0; j < 4; ++j)
            *(unsigned int*)(&Ys[0][(w * 16 + u * 4 + j) * ROWB + l * 4]) = pk2(f0[j], f1[j]);
    }

    // A-read offsets (loop-invariant): A[m=key=n16][k=quad*8+j], row = w*16+n16
    int aoff[4];
    #pragma unroll
    for (int cc = 0; cc < 4; ++cc)
        aoff[cc] = (w * 16 + n16) * ROWB + (cc * 4 + quad) * 16;

    // D rows of this lane: tile-local keys w*16 + quad*4 + r
    float gxr[4];
    #pragma unroll
    for (int r = 0; r < 4; ++r) gxr[r] = (float)(w * 16 + quad * 4 + r) + 0.5f;

    float den[4] = {0.f, 0.f, 0.f, 0.f}, nu[4] = {0.f, 0.f, 0.f, 0.f}, nv[4] = {0.f, 0.f, 0.f, 0.f};

    for (int kt = 0; kt < 64; ++kt) {
        char* cur = Ys[kt & 1];
        char* nxt = Ys[(kt & 1) ^ 1];

        __syncthreads();   // buf cur fully written; all waves done reading buf nxt (prev iter)

        // prefetch next tile into regs — consumed after the MFMA block (~600 cyc later)
        float4 a0[4], a1[4];
        if (kt < 63) {
            const float* rp = yb + (kt + 1) * 64;
            #pragma unroll
            for (int u = 0; u < 4; ++u) {
                a0[u] = *(const float4*)(rp + u * 4);
                a1[u] = *(const float4*)(rp + NPIX + u * 4);
            }
        }

        f32x4 acc[4];
        #pragma unroll
        for (int qg = 0; qg < 4; ++qg) acc[qg] = (f32x4){0.f, 0.f, 0.f, 0.f};

        #pragma unroll
        for (int cc = 0; cc < 4; ++cc) {
            const f16x8 A = *(const f16x8*)(cur + aoff[cc]);
            #pragma unroll
            for (int qg = 0; qg < 4; ++qg) {
                acc[qg] = __builtin_amdgcn_mfma_f32_16x16x32_f16(A, bh[cc][qg], acc[qg], 0, 0, 0);
                acc[qg] = __builtin_amdgcn_mfma_f32_16x16x32_f16(A, bl[cc][qg], acc[qg], 0, 0, 0);
            }
        }

        // softmax accumulation, no max subtraction (|s| <= ~7 -> exp safe in fp32)
        const float gy = (float)kt + 0.5f;
        #pragma unroll
        for (int qg = 0; qg < 4; ++qg) {
            float ps = 0.f, px = 0.f;
            #pragma unroll
            for (int r = 0; r < 4; ++r) {
                const float p = __expf(acc[qg][r]);
                ps += p;
                px += p * gxr[r];
            }
            den[qg] += ps;
            nu[qg]  += px;
            nv[qg]  += gy * ps;
        }

        // convert + write next tile into the other buffer (2-way LDS aliasing = free)
        if (kt < 63) {
            #pragma unroll
            for (int u = 0; u < 4; ++u) {
                const float* f0 = (const float*)&a0[u];
                const float* f1 = (const float*)&a1[u];
                #pragma unroll
                for (int j = 0; j < 4; ++j)
                    *(unsigned int*)(&nxt[(w * 16 + u * 4 + j) * ROWB + l * 4]) = pk2(f0[j], f1[j]);
            }
        }
    }

    // ---- reduce over this wave's 16 keys (quad bits), then across waves via LDS ----
    #pragma unroll
    for (int qg = 0; qg < 4; ++qg) {
        #pragma unroll
        for (int mk = 16; mk <= 32; mk <<= 1) {
            den[qg] += __shfl_xor(den[qg], mk);
            nu[qg]  += __shfl_xor(nu[qg],  mk);
            nv[qg]  += __shfl_xor(nv[qg],  mk);
        }
    }
    __syncthreads();                  // done with Ys — reuse as reduce scratch
    float* red = (float*)&Ys[0][0];   // [4 waves][64 queries][3]
    if (quad == 0) {
        #pragma unroll
        for (int qg = 0; qg < 4; ++qg) {
            const int base = (w * 64 + qg * 16 + n16) * 3;
            red[base + 0] = den[qg];
            red[base + 1] = nu[qg];
            red[base + 2] = nv[qg];
        }
    }
    __syncthreads();
    if (t < 64) {
        float d = 0.f, u = 0.f, v = 0.f;
        #pragma unroll
        for (int ww = 0; ww < 4; ++ww) {
            d += red[(ww * 64 + t) * 3 + 0];
            u += red[(ww * 64 + t) * 3 + 1];
            v += red[(ww * 64 + t) * 3 + 2];
        }
        const float inv = 1.0f / d;
        *(float2*)(out + ((size_t)b * NPIX + q0 + t) * 2) =
            make_float2(u * inv * 0.03125f - 1.0f, v * inv * 0.03125f - 1.0f);
    }
}

extern "C" void kernel_launch(void* const* d_in, const int* in_sizes, int n_in,
                              void* d_out, int out_size, void* d_ws, size_t ws_size,
                              hipStream_t stream) {
    const float* x = (const float*)d_in[0];
    const float* y = (const float*)d_in[1];
    float* out = (float*)d_out;
    hipLaunchKernelGGL(uv_fused, dim3(256), dim3(256), 0, stream, x, y, out);
}

// Round 7
// 104.730 us; speedup vs baseline: 1.6133x; 1.6133x over previous
//
#include <hip/hip_runtime.h>
#include <math.h>

typedef __attribute__((ext_vector_type(8))) _Float16 f16x8;
typedef __attribute__((ext_vector_type(4))) float f32x4;

#define NPIX 4096
#define C_DIM 128
#define SCALE 0.08838834764831845f   // 1/sqrt(128), folded into X hi/lo split

// ws: fp16 Y panel [b][k][c], rows of 256B, granule-XOR swizzled. 4 MB total.
#define WS_NEED ((size_t)4 << 20)

// ---------------- conv: y fp32 [c][k] -> fp16 panel [k][c], XCD-matched ----------------
__global__ __launch_bounds__(256) void conv_y(const float* __restrict__ y,
                                              char* __restrict__ ws)
{
    __shared__ float T[32][132];     // [k][c] fp32 scratch, padded
    const int wg  = blockIdx.x;
    const int xcd = wg & 7;
    const int b   = xcd >> 1;                        // same batch->XCD map as main
    const int sl  = ((xcd & 1) << 6) | (wg >> 3);    // 0..127 key slice
    const int k0  = sl * 32;
    const int t   = threadIdx.x;

    {   // read 128c x 32k, coalesced (thread-pairs cover 128B rows)
        const int c = t >> 1, half = t & 1;
        const float* srow = y + ((size_t)b * C_DIM + c) * NPIX + k0 + half * 16;
        float4 rv[4];
        #pragma unroll
        for (int u = 0; u < 4; ++u) rv[u] = *(const float4*)(srow + u * 4);
        #pragma unroll
        for (int u = 0; u < 4; ++u) {
            T[half * 16 + u * 4 + 0][c] = rv[u].x;
            T[half * 16 + u * 4 + 1][c] = rv[u].y;
            T[half * 16 + u * 4 + 2][c] = rv[u].z;
            T[half * 16 + u * 4 + 3][c] = rv[u].w;
        }
    }
    __syncthreads();

    char* panel = ws + (size_t)b * (NPIX * 256);
    const int k = t >> 3, g2 = t & 7;               // key-local, granule pair
    f16x8 v0, v1;
    #pragma unroll
    for (int m = 0; m < 8; ++m) {
        v0[m] = (_Float16)T[k][g2 * 16 + m];
        v1[m] = (_Float16)T[k][g2 * 16 + 8 + m];
    }
    const int key = k0 + k, s = key & 7;            // granule-XOR swizzle per key row
    char* drow = panel + (size_t)key * 256;
    *(f16x8*)(drow + (((2 * g2)     ^ s) << 4)) = v0;
    *(f16x8*)(drow + (((2 * g2 + 1) ^ s) << 4)) = v1;
}

// ---------------- main: S^T MFMA. A = Y fp16 (global_load_lds dbuf), B = X hi/lo regs ----------------
// grid 512 = 2 blocks/CU (2 waves/SIMD). TQ=32 -> B-frags only 64 VGPRs (no-spill regime).
// TK=128 keys/tile, 32 tiles, 1 barrier/tile; each wave stages exactly its own A rows.
__global__ __launch_bounds__(256, 2) void uv_main(const char* __restrict__ ws,
                                                  const float* __restrict__ x,
                                                  float* __restrict__ out)
{
    __shared__ __align__(16) char Ys[2][32768];     // dbuf: 128 keys x 256B fp16

    const int t = threadIdx.x, w = t >> 6, l = t & 63;
    const int n16 = l & 15, quad = l >> 4;
    const int wg  = blockIdx.x;
    const int xcd = wg & 7;
    const int b   = xcd >> 1;                       // 2 XCDs per batch, panel 1MB -> L2-resident
    const int qt  = ((xcd & 1) << 6) | (wg >> 3);   // 0..127
    const int q0  = qt * 32;

    // ---- one-time: X B-fragments fp16 hi/lo (exact split, scale folded). 64 VGPRs. ----
    f16x8 bh[4][2], bl[4][2];                       // [cc][qg]
    {
        const float* xb = x + (size_t)b * C_DIM * NPIX + q0 + n16;
        #pragma unroll
        for (int cc = 0; cc < 4; ++cc)
            #pragma unroll
            for (int qg = 0; qg < 2; ++qg) {
                f16x8 hh, ll;
                #pragma unroll
                for (int j = 0; j < 8; ++j) {
                    const float f = xb[(size_t)(cc * 32 + quad * 8 + j) * NPIX + qg * 16] * SCALE;
                    const _Float16 fh = (_Float16)f;
                    hh[j] = fh;
                    ll[j] = (_Float16)(f - (float)fh);
                }
                bh[cc][qg] = hh;
                bl[cc][qg] = ll;
            }
    }

    const char* panel = ws + (size_t)b * (NPIX * 256);

    // A-read LDS offsets (loop-invariant): row = mt*64 + w*16 + n16, swizzled granules
    int aoff[2][4];
    #pragma unroll
    for (int mt = 0; mt < 2; ++mt)
        #pragma unroll
        for (int cc = 0; cc < 4; ++cc)
            aoff[mt][cc] = (mt * 64 + w * 16 + n16) * 256 + (((cc * 4 + quad) ^ (n16 & 7)) << 4);

    // D rows of this lane: tile-local key (within 64-group) = w*16 + quad*4 + r
    float gxr[4];
    #pragma unroll
    for (int r = 0; r < 4; ++r) gxr[r] = (float)(w * 16 + quad * 4 + r) + 0.5f;

    float den[2] = {0.f, 0.f}, nu[2] = {0.f, 0.f}, nv[2] = {0.f, 0.f};

    // staging: wave w copies its own A rows (mt*64 + w*16 .. +16) of each 128-key tile
    #pragma unroll
    for (int h = 0; h < 2; ++h)       // preload tile 0 into buf 0
        #pragma unroll
        for (int i = 0; i < 4; ++i) {
            const int off = (h * 64 + w * 16 + i * 4) * 256;
            __builtin_amdgcn_global_load_lds(
                (const __attribute__((address_space(1))) void*)(panel + off + l * 16),
                (__attribute__((address_space(3))) void*)(&Ys[0][off]), 16, 0, 0);
        }

    #pragma unroll 2
    for (int kt = 0; kt < 32; ++kt) {
        const int cur = kt & 1;
        __syncthreads();   // drains this wave's buf[cur] loads; all waves off buf[cur^1]

        if (kt < 31) {     // issue NEXT tile into other buffer — lands during compute
            const char* gt = panel + (size_t)(kt + 1) * 32768;
            #pragma unroll
            for (int h = 0; h < 2; ++h)
                #pragma unroll
                for (int i = 0; i < 4; ++i) {
                    const int off = (h * 64 + w * 16 + i * 4) * 256;
                    __builtin_amdgcn_global_load_lds(
                        (const __attribute__((address_space(1))) void*)(gt + off + l * 16),
                        (__attribute__((address_space(3))) void*)(&Ys[cur ^ 1][off]), 16, 0, 0);
                }
        }

        f32x4 acc[2][2];
        #pragma unroll
        for (int mt = 0; mt < 2; ++mt)
            #pragma unroll
            for (int qg = 0; qg < 2; ++qg) acc[mt][qg] = (f32x4){0.f, 0.f, 0.f, 0.f};

        #pragma unroll
        for (int cc = 0; cc < 4; ++cc) {
            const f16x8 A0 = *(const f16x8*)(&Ys[cur][aoff[0][cc]]);
            const f16x8 A1 = *(const f16x8*)(&Ys[cur][aoff[1][cc]]);
            #pragma unroll
            for (int qg = 0; qg < 2; ++qg) {
                acc[0][qg] = __builtin_amdgcn_mfma_f32_16x16x32_f16(A0, bh[cc][qg], acc[0][qg], 0, 0, 0);
                acc[0][qg] = __builtin_amdgcn_mfma_f32_16x16x32_f16(A0, bl[cc][qg], acc[0][qg], 0, 0, 0);
                acc[1][qg] = __builtin_amdgcn_mfma_f32_16x16x32_f16(A1, bh[cc][qg], acc[1][qg], 0, 0, 0);
                acc[1][qg] = __builtin_amdgcn_mfma_f32_16x16x32_f16(A1, bl[cc][qg], acc[1][qg], 0, 0, 0);
            }
        }

        // softmax accumulation, no max subtraction (|s| <= ~7 -> exp safe in fp32)
        #pragma unroll
        for (int qg = 0; qg < 2; ++qg) {
            float d = 0.f, u = 0.f, v = 0.f;
            #pragma unroll
            for (int mt = 0; mt < 2; ++mt) {
                const float gy = (float)(kt * 2 + mt) + 0.5f;
                #pragma unroll
                for (int r = 0; r < 4; ++r) {
                    const float p = __expf(acc[mt][qg][r]);
                    d += p;
                    u += p * gxr[r];
                    v += p * gy;
                }
            }
            den[qg] += d; nu[qg] += u; nv[qg] += v;
        }
    }

    // ---- reduce: across quads (keys) then across waves via LDS ----
    #pragma unroll
    for (int qg = 0; qg < 2; ++qg) {
        #pragma unroll
        for (int mk = 16; mk <= 32; mk <<= 1) {
            den[qg] += __shfl_xor(den[qg], mk);
            nu[qg]  += __shfl_xor(nu[qg],  mk);
            nv[qg]  += __shfl_xor(nv[qg],  mk);
        }
    }
    __syncthreads();                  // done with Ys — reuse as reduce scratch
    float* red = (float*)&Ys[0][0];   // [4 waves][32 queries][3]
    if (quad == 0) {
        #pragma unroll
        for (int qg = 0; qg < 2; ++qg) {
            const int base = (w * 32 + qg * 16 + n16) * 3;
            red[base + 0] = den[qg];
            red[base + 1] = nu[qg];
            red[base + 2] = nv[qg];
        }
    }
    __syncthreads();
    if (t < 32) {
        float d = 0.f, u = 0.f, v = 0.f;
        #pragma unroll
        for (int ww = 0; ww < 4; ++ww) {
            d += red[(ww * 32 + t) * 3 + 0];
            u += red[(ww * 32 + t) * 3 + 1];
            v += red[(ww * 32 + t) * 3 + 2];
        }
        const float inv = 1.0f / d;
        *(float2*)(out + ((size_t)b * NPIX + q0 + t) * 2) =
            make_float2(u * inv * 0.03125f - 1.0f, v * inv * 0.03125f - 1.0f);
    }
}

// ---------------- fallback (fp32 vector kernel, known-correct) if ws too small ----------------
__global__ __launch_bounds__(256, 2) void uv_attn_kernel(
    const float* __restrict__ x, const float* __restrict__ y, float* __restrict__ out)
{
    __shared__ float Xs[C_DIM][32];
    __shared__ float Ysf[64][128];
    const int tid = threadIdx.x;
    const int wgid = blockIdx.x;
    const int xcd = wgid & 7;
    const int b = xcd & 3;
    const int q0 = (((xcd >> 2) << 6) | (wgid >> 3)) * 32;
    const float* xb = x + (size_t)b * C_DIM * NPIX + q0;
    {
        const int cr = tid >> 3;
        const int cc = (tid & 7) << 2;
        #pragma unroll
        for (int i = 0; i < 4; ++i) {
            float4 v = *(const float4*)(xb + (size_t)(cr + (i << 5)) * NPIX + cc);
            v.x *= SCALE; v.y *= SCALE; v.z *= SCALE; v.w *= SCALE;
            *(float4*)(&Xs[cr + (i << 5)][cc]) = v;
        }
    }
    const int rg = tid >> 4;
    const int lane16 = tid & 15;
    const int r0 = rg << 1;
    const int col0 = lane16 << 3;
    float gxv[8];
    #pragma unroll
    for (int j2 = 0; j2 < 8; ++j2) gxv[j2] = (float)((col0 & 63) + j2) + 0.5f;
    const float gyb = (float)(lane16 >> 3) + 0.5f;
    float m_run[2] = {-INFINITY, -INFINITY};
    float den[2] = {0.f, 0.f}, nu[2] = {0.f, 0.f}, nv[2] = {0.f, 0.f};
    const int yr = tid >> 5;
    const int yc = (tid & 31) << 2;
    const float* ybase = y + (size_t)b * C_DIM * NPIX;
    for (int kt = 0; kt < 32; ++kt) {
        float S[2][8];
        #pragma unroll
        for (int r = 0; r < 2; ++r)
            #pragma unroll
            for (int j2 = 0; j2 < 8; ++j2) S[r][j2] = 0.f;
        #pragma unroll
        for (int cb = 0; cb < 2; ++cb) {
            __syncthreads();
            const float* yt = ybase + (size_t)(cb << 6) * NPIX + kt * 128;
            #pragma unroll
            for (int i = 0; i < 8; ++i)
                *(float4*)(&Ysf[yr + (i << 3)][yc]) =
                    *(const float4*)(yt + (size_t)(yr + (i << 3)) * NPIX + yc);
            __syncthreads();
            const int cbase = cb << 6;
            #pragma unroll 16
            for (int c = 0; c < 64; ++c) {
                const float2 xa = *(const float2*)(&Xs[cbase + c][r0]);
                const float4 ya = *(const float4*)(&Ysf[c][col0]);
                const float4 yb4 = *(const float4*)(&Ysf[c][col0 + 4]);
                S[0][0] += xa.x * ya.x;  S[0][1] += xa.x * ya.y;
                S[0][2] += xa.x * ya.z;  S[0][3] += xa.x * ya.w;
                S[0][4] += xa.x * yb4.x; S[0][5] += xa.x * yb4.y;
                S[0][6] += xa.x * yb4.z; S[0][7] += xa.x * yb4.w;
                S[1][0] += xa.y * ya.x;  S[1][1] += xa.y * ya.y;
                S[1][2] += xa.y * ya.z;  S[1][3] += xa.y * ya.w;
                S[1][4] += xa.y * yb4.x; S[1][5] += xa.y * yb4.y;
                S[1][6] += xa.y * yb4.z; S[1][7] += xa.y * yb4.w;
            }
        }
        const float gy = gyb + 2.0f * (float)kt;
        #pragma unroll
        for (int r = 0; r < 2; ++r) {
            float tmax = S[r][0];
            #pragma unroll
            for (int j2 = 1; j2 < 8; ++j2) tmax = fmaxf(tmax, S[r][j2]);
            #pragma unroll
            for (int mk = 8; mk >= 1; mk >>= 1) tmax = fmaxf(tmax, __shfl_xor(tmax, mk, 16));
            const float mnew = fmaxf(m_run[r], tmax);
            const float alpha = __expf(m_run[r] - mnew);
            m_run[r] = mnew;
            float psum = 0.f, pu = 0.f;
            #pragma unroll
            for (int j2 = 0; j2 < 8; ++j2) {
                const float p = __expf(S[r][j2] - mnew);
                psum += p; pu += p * gxv[j2];
            }
            den[r] = den[r] * alpha + psum;
            nu[r] = nu[r] * alpha + pu;
            nv[r] = nv[r] * alpha + gy * psum;
        }
    }
    #pragma unroll
    for (int r = 0; r < 2; ++r)
        #pragma unroll
        for (int mk = 8; mk >= 1; mk >>= 1) {
            den[r] += __shfl_xor(den[r], mk, 16);
            nu[r] += __shfl_xor(nu[r], mk, 16);
            nv[r] += __shfl_xor(nv[r], mk, 16);
        }
    if (lane16 == 0) {
        #pragma unroll
        for (int r = 0; r < 2; ++r) {
            const float inv = 1.0f / den[r];
            const int q = q0 + r0 + r;
            *(float2*)(out + ((size_t)b * NPIX + q) * 2) =
                make_float2(nu[r] * inv * 0.03125f - 1.0f, nv[r] * inv * 0.03125f - 1.0f);
        }
    }
}

extern "C" void kernel_launch(void* const* d_in, const int* in_sizes, int n_in,
                              void* d_out, int out_size, void* d_ws, size_t ws_size,
                              hipStream_t stream) {
    const float* x = (const float*)d_in[0];
    const float* y = (const float*)d_in[1];
    float* out = (float*)d_out;
    if (ws_size >= WS_NEED) {
        hipLaunchKernelGGL(conv_y, dim3(512), dim3(256), 0, stream, y, (char*)d_ws);
        hipLaunchKernelGGL(uv_main, dim3(512), dim3(256), 0, stream,
                           (const char*)d_ws, x, out);
    } else {
        hipLaunchKernelGGL(uv_attn_kernel, dim3(512), dim3(256), 0, stream, x, y, out);
    }
}